// Round 4
// baseline (287.054 us; speedup 1.0000x reference)
//
#include <hip/hip_runtime.h>

// vol[n,d,h,w] = sum_c L[n,c,h,w] * R[n,c,h,w-d], 0 if w<d
// N=4, C=128, H=160, W=320, D=48, fp32 in/out.
//
// Fully wave-independent MFMA formulation — no staging, no barriers:
//  - 3200 blocks x 256 thr; each of the 4 waves owns one 16-w output tile
//    (w0 = 64*grp + 16*wid), 12800 independent waves.
//  - A (L) and B (R) fragments both loaded DIRECTLY global->reg as scalar
//    dwords (16 lanes x consecutive w/j = coalesced 64 B segments), packed
//    f32->f16 with cvt_pkrtz. R is logically re-read ~4x; L2/L3 absorb it
//    (XCD-chunked block swizzle keeps a row's reuse on one XCD).
//  - 16 x mfma_f32_16x16x32_f16 per wave (4 disjoint j-tiles x K=128).
//    Left-edge j<0 tiles: clamped address + wave-uniform cndmask zero of B.
//  - Band-masked epilogue transposes through per-wave LDS scratch (3.8 KB)
//    so global stores are float4 along w. No __syncthreads anywhere.

#define NN 4
#define CC 128
#define HH 160
#define WW 320
#define DD 48
#define HWs (HH * WW)
#define NTH 256
#define GRID 3200  // 640 (n,h) rows x 5 groups of 64 w

typedef _Float16 h2 __attribute__((ext_vector_type(2)));
typedef _Float16 f16x8 __attribute__((ext_vector_type(8)));
typedef float f32x4 __attribute__((ext_vector_type(4)));
typedef __fp16 h2raw __attribute__((ext_vector_type(2)));

__device__ __forceinline__ h2 pack2(float a, float b) {
  union { h2raw r; h2 h; } u;
  u.r = __builtin_amdgcn_cvt_pkrtz(a, b);  // v_cvt_pkrtz_f16_f32
  return u.h;
}

__global__ __launch_bounds__(NTH, 4)
void corr_kernel(const float* __restrict__ L, const float* __restrict__ R,
                 float* __restrict__ out) {
  __shared__ __align__(16) float Ep[4][DD * 20];  // per-wave scratch, 15.4 KB

  const int tid = threadIdx.x;
  const int wid = tid >> 6;
  const int ln  = tid & 63;
  const int i16 = ln & 15;   // frag m/n index
  const int g   = ln >> 4;   // k-group 0..3

  // XCD-chunked bijective swizzle (3200 = 8 x 400): each XCD gets 80
  // contiguous (n,h) rows -> R overlap + L lines stay in its L2.
  const int hwb = blockIdx.x;
  const int bid = (hwb & 7) * (GRID / 8) + (hwb >> 3);

  const int row = bid / 5;  // (n,h)
  const int grp = bid - 5 * row;
  const int n = row / HH;
  const int h = row - n * HH;
  const int w0 = 64 * grp + 16 * wid;

  const size_t base = (size_t)n * CC * HWs + (size_t)h * WW;
  const float* Lp = L + base + w0 + i16;
  const float* Rp = R + base + i16;

  union AU { f16x8 v; h2 h[4]; };

  // ---- A: global->reg (c = 32ks+8g+e at w = w0+i16), pack pairs of c
  float la[32];
#pragma unroll
  for (int ks = 0; ks < 4; ++ks)
#pragma unroll
    for (int e = 0; e < 8; ++e)
      la[ks * 8 + e] = Lp[(size_t)(32 * ks + 8 * g + e) * HWs];
  AU A[4];
#pragma unroll
  for (int ks = 0; ks < 4; ++ks)
#pragma unroll
    for (int j = 0; j < 4; ++j)
      A[ks].h[j] = pack2(la[ks * 8 + 2 * j], la[ks * 8 + 2 * j + 1]);

  f32x4 acc[4];
#pragma unroll
  for (int q = 0; q < 4; ++q) acc[q] = (f32x4){0.f, 0.f, 0.f, 0.f};

  // ---- 4 disjoint j-tiles: j0 = w0-48+16q; B same frag shape as A
#pragma unroll
  for (int q = 0; q < 4; ++q) {
    const int j0 = w0 - 48 + 16 * q;
    const bool ok = (j0 >= 0);            // wave-uniform (j0 mult of 16)
    const float* rp = Rp + (ok ? j0 : 0); // clamped: loads stay in-bounds
    float rb[32];
#pragma unroll
    for (int ks = 0; ks < 4; ++ks)
#pragma unroll
      for (int e = 0; e < 8; ++e)
        rb[ks * 8 + e] = rp[(size_t)(32 * ks + 8 * g + e) * HWs];
    const h2 z = pack2(0.f, 0.f);
#pragma unroll
    for (int ks = 0; ks < 4; ++ks) {
      AU B;
#pragma unroll
      for (int j = 0; j < 4; ++j)
        B.h[j] = ok ? pack2(rb[ks * 8 + 2 * j], rb[ks * 8 + 2 * j + 1]) : z;
      acc[q] = __builtin_amdgcn_mfma_f32_16x16x32_f16(A[ks].v, B.v, acc[q], 0, 0, 0);
    }
  }

  // ---- epilogue: lane holds D[m=4g+r][n=i16] -> w = w0+4g+r,
  // d = 48-16q+4g+r-i16 (disjoint exact cover of d in [0,48) over q).
  // Transpose via per-wave LDS scratch -> float4 stores along w.
  // Own-wave write->read; compiler inserts the lgkmcnt wait.
  float* ep = Ep[wid];
#pragma unroll
  for (int q = 0; q < 4; ++q)
#pragma unroll
    for (int r = 0; r < 4; ++r) {
      int d = 48 - 16 * q + 4 * g + r - i16;
      if (d >= 0 && d < DD) ep[d * 20 + 4 * g + r] = acc[q][r];
    }

  const int l4 = ln & 3;
  const int dr = ln >> 2;  // 0..15
  float* op = out + (size_t)n * DD * HWs + (size_t)h * WW + w0 + 4 * l4;
#pragma unroll
  for (int rr = 0; rr < 3; ++rr) {
    int d = 16 * rr + dr;
    *(float4*)&op[(size_t)d * HWs] = *(const float4*)&ep[d * 20 + 4 * l4];
  }
}

extern "C" void kernel_launch(void* const* d_in, const int* in_sizes, int n_in,
                              void* d_out, int out_size, void* d_ws, size_t ws_size,
                              hipStream_t stream) {
  const float* L = (const float*)d_in[0];
  const float* R = (const float*)d_in[1];
  float* out = (float*)d_out;
  corr_kernel<<<dim3(GRID), dim3(NTH), 0, stream>>>(L, R, out);
}

// Round 5
// 245.070 us; speedup vs baseline: 1.1713x; 1.1713x over previous
//
#include <hip/hip_runtime.h>
#include <stdint.h>

// vol[n,d,h,w] = sum_c L[n,c,h,w] * R[n,c,h,w-d], 0 if w<d
// N=4, C=128, H=160, W=320, D=48, fp32 in/out.
//
// Banded-GEMM, m97-style streaming revision:
//  - 1280 blocks = (n,h) x 2 w-halves (minimal R halo), 640 thr / 10 waves;
//    wave wt owns w-tile [wb+16wt, +16).
//  - R staged f32 by global_load_lds width-16 (HBM->LDS DMA, no VGPR trip)
//    into linear [32 c][208 j] chunk buffers, double-buffered (53.2 KB ->
//    3 blocks/CU = 30 waves/CU, phase-staggered streaming).
//  - 4 K-chunks of 32 c; per chunk: issue DMA(k+1) + L(k+1), compute(k)
//    (4 q-tiles x mfma_f32_16x16x32_f16, frags cvt'd f32->f16 at read),
//    one barrier. K-element map c-local=4e+g makes frag ds_reads 2
//    lanes/bank (conflict-free).
//  - Left-edge j<0: loads clamped; garbage only reaches d>w outputs, which
//    the epilogue overwrites with the reference's zero padding (d<=w mask).
//  - Epilogue transposes through LDS (reusing chunk buffers) -> float4
//    stores along w.

#define NN 4
#define CC 128
#define HH 160
#define WW 320
#define DD 48
#define HWs (HH * WW)
#define WB 160
#define RJ 208          // j-window floats per c-row: [wb-48, wb+160)
#define CK 32           // channels per chunk
#define CHF (CK * RJ)   // floats per chunk buffer = 6656
#define NTH 640
#define GRID 1280

typedef _Float16 h2 __attribute__((ext_vector_type(2)));
typedef _Float16 f16x8 __attribute__((ext_vector_type(8)));
typedef float f32x4 __attribute__((ext_vector_type(4)));
typedef __fp16 h2raw __attribute__((ext_vector_type(2)));

__device__ __forceinline__ h2 pack2(float a, float b) {
  union { h2raw r; h2 h; } u;
  u.r = __builtin_amdgcn_cvt_pkrtz(a, b);  // v_cvt_pkrtz_f16_f32
  return u.h;
}

__device__ __forceinline__ void gl_lds16(const float* g, float* l) {
  __builtin_amdgcn_global_load_lds(
      (const __attribute__((address_space(1))) uint32_t*)g,
      (__attribute__((address_space(3))) uint32_t*)l, 16, 0, 0);
}

__global__ __launch_bounds__(NTH, 8)
void corr_kernel(const float* __restrict__ L, const float* __restrict__ R,
                 float* __restrict__ out) {
  // 53,248 B: 2 chunk buffers; reused as epilogue scratch (10 x 960 f32).
  __shared__ __align__(16) float S[2 * CHF];

  const int tid = threadIdx.x;
  const int wt  = tid >> 6;   // wave id == w-tile 0..9
  const int ln  = tid & 63;
  const int i16 = ln & 15;    // frag m/n index
  const int g   = ln >> 4;    // k-group 0..3

  // XCD-chunked bijective swizzle (1280 = 8 x 160)
  const int raw = blockIdx.x;
  const int bid = (raw & 7) * (GRID / 8) + (raw >> 3);
  const int wsplit = bid & 1;
  const int rnh = bid >> 1;
  const int n = rnh / HH;
  const int h = rnh - n * HH;
  const int wb = wsplit * WB;

  const size_t base = (size_t)n * CC * HWs + (size_t)h * WW;
  const float* Rb = R + base;
  const float* Lb = L + base + wb + 16 * wt + i16;

  // ---- staging task decomposition: 1664 tasks/chunk = 32 c x 52 j-blocks.
  // thread t handles tasks t, t+640 (all threads) and t+1280 (waves 0..5).
  // LDS dest is linear 16B/task -> DMA-compatible ([c][j] pitch 208 exactly).
  const int t0 = tid, t1 = tid + 640, t2 = tid + 1280;
  const int c0 = t0 / 52, v0 = t0 - 52 * c0;
  const int c1 = t1 / 52, v1 = t1 - 52 * c1;
  const int c2 = t2 / 52, v2 = t2 - 52 * c2;
  int col0 = wb - 48 + 4 * v0; if (col0 < 0) col0 = 0;  // clamp (see epilogue)
  int col1 = wb - 48 + 4 * v1; if (col1 < 0) col1 = 0;
  int col2 = wb - 48 + 4 * v2; if (col2 < 0) col2 = 0;
  const float* gp0 = Rb + (size_t)c0 * HWs + col0;
  const float* gp1 = Rb + (size_t)c1 * HWs + col1;
  const float* gp2 = Rb + (size_t)c2 * HWs + col2;

  float lv[2][8];

  auto stage = [&](int kk) {  // kk is a literal (unrolled callers)
    float* dst = S + (kk & 1) * CHF;
    const size_t coff = (size_t)(CK * kk) * HWs;
    gl_lds16(gp0 + coff, dst + 4 * t0);
    gl_lds16(gp1 + coff, dst + 4 * t1);
    if (wt < 6) gl_lds16(gp2 + coff, dst + 4 * t2);  // wave-uniform branch
  };
  auto lload = [&](int kk) {  // L chunk kk: c = 32kk + 4e + g
    const float* p = Lb + (size_t)(CK * kk) * HWs;
#pragma unroll
    for (int e = 0; e < 8; ++e)
      lv[kk & 1][e] = p[(size_t)(4 * e + g) * HWs];
  };

  // ---- prologue
  stage(0);
  lload(0);
  __syncthreads();  // drains DMA + L loads for chunk 0

  f32x4 acc[4];
#pragma unroll
  for (int q = 0; q < 4; ++q) acc[q] = (f32x4){0.f, 0.f, 0.f, 0.f};

  // ---- 4 chunks, software-pipelined; one barrier per chunk
#pragma unroll
  for (int k = 0; k < 4; ++k) {
    if (k < 3) { stage(k + 1); lload(k + 1); }  // in flight across compute

    // A frag: element e <-> c-local 4e+g; pack pairs (2j, 2j+1)
    union AU { f16x8 v; h2 h[4]; } A;
#pragma unroll
    for (int j = 0; j < 4; ++j)
      A.h[j] = pack2(lv[k & 1][2 * j], lv[k & 1][2 * j + 1]);

    const float* Bb = S + (k & 1) * CHF;
#pragma unroll
    for (int q = 0; q < 4; ++q) {
      const int s = 16 * (wt + q) + i16;  // j-window col, in [0, 208)
      union BU { f16x8 v; h2 h[4]; } B;
#pragma unroll
      for (int j = 0; j < 4; ++j)         // rows 8j+g, 8j+4+g: 2 lanes/bank
        B.h[j] = pack2(Bb[(8 * j + g) * RJ + s], Bb[(8 * j + 4 + g) * RJ + s]);
      acc[q] = __builtin_amdgcn_mfma_f32_16x16x32_f16(A.v, B.v, acc[q], 0, 0, 0);
    }
    __syncthreads();  // drains DMA(k+1); frees buf (k&1) for DMA(k+2)
  }

  // ---- epilogue: lane holds D[m=4g+r][n=i16] -> w = wb+16wt+4g+r,
  // d = 48-16q+4g+r-i16 (disjoint exact cover of d in [0,48) over q).
  // d > w outputs are the reference's zero padding (and the only places
  // clamped-load garbage can land) -> store 0 there. Transpose through
  // LDS scratch (chunk buffers, all reads done) -> float4 stores along w.
  float* ep = S + wt * (DD * 20);
  const int wl = wb + 16 * wt;
#pragma unroll
  for (int q = 0; q < 4; ++q)
#pragma unroll
    for (int r = 0; r < 4; ++r) {
      const int m = 4 * g + r;
      const int d = 48 - 16 * q + m - i16;
      if (d >= 0 && d < DD) ep[d * 20 + m] = (d <= wl + m) ? acc[q][r] : 0.f;
    }
  // own-wave write->read; compiler inserts the lgkmcnt wait

  const int l4 = ln & 3;
  const int dr = ln >> 2;  // 0..15
  float* op = out + (size_t)n * DD * HWs + (size_t)h * WW + wl + 4 * l4;
#pragma unroll
  for (int rr = 0; rr < 3; ++rr) {
    const int d = 16 * rr + dr;
    *(float4*)&op[(size_t)d * HWs] = *(const float4*)&ep[d * 20 + 4 * l4];
  }
}

extern "C" void kernel_launch(void* const* d_in, const int* in_sizes, int n_in,
                              void* d_out, int out_size, void* d_ws, size_t ws_size,
                              hipStream_t stream) {
  const float* L = (const float*)d_in[0];
  const float* R = (const float*)d_in[1];
  float* out = (float*)d_out;
  corr_kernel<<<dim3(GRID), dim3(NTH), 0, stream>>>(L, R, out);
}